// Round 2
// baseline (11850.636 us; speedup 1.0000x reference)
//
#include <hip/hip_runtime.h>
#include <hip/hip_bf16.h>
#include <math.h>

constexpr int BATCH = 8;
constexpr int IMG_H = 64;
constexpr int IMG_W = 512;
constexpr int DIM   = 128;
constexpr int WIN_H = 4, WIN_W = 32;
constexpr int SHIFT_H = 2, SHIFT_W = 2;
constexpr int NTOK = 128;            // tokens per window
constexpr int HEADS = 4, HD = 32;
constexpr float QK_SCALE = 0.17677669529663687f;   // 1/sqrt(32)

__device__ __forceinline__ float bf2f(unsigned short u) {
    return __uint_as_float(((unsigned)u) << 16);
}
__device__ __forceinline__ float bflo(unsigned u) { return __uint_as_float(u << 16); }
__device__ __forceinline__ float bfhi(unsigned u) { return __uint_as_float(u & 0xffff0000u); }
__device__ __forceinline__ unsigned short f2bf(float f) {
    unsigned u = __float_as_uint(f);
    u = (u + 0x7fffu + ((u >> 16) & 1u)) >> 16;   // RNE; inputs are well-behaved (no NaN)
    return (unsigned short)u;
}
// dtype-adaptive global load/store: f32 flag is wave-uniform (sniffed from g1/g2 == ones)
__device__ __forceinline__ float ld(const void* p, size_t i, bool f32) {
    return f32 ? ((const float*)p)[i] : bf2f(((const unsigned short*)p)[i]);
}
__device__ __forceinline__ void st(void* p, size_t i, bool f32, float v) {
    if (f32) ((float*)p)[i] = v;
    else     ((unsigned short*)p)[i] = f2bf(v);
}

// ---------------------------------------------------------------------------
// Kernel 1: LN1 + cyclic shift + window attention + proj + residual
// One block (256 threads) per window. 2048 blocks.
// ---------------------------------------------------------------------------
__global__ __launch_bounds__(256) void swin_attn_kernel(
    const void* __restrict__ x,
    const void* __restrict__ g1,
    const void* __restrict__ b1,
    const void* __restrict__ qkv_w,
    const void* __restrict__ qkv_b,
    const void* __restrict__ rpb,
    const void* __restrict__ proj_w,
    const void* __restrict__ proj_b,
    void* __restrict__ out)
{
    __shared__ __align__(16) unsigned short s_xw[NTOK][DIM];  // LN'd tokens, later reused for proj_w
    __shared__ float s_q[NTOK][HD + 1];
    __shared__ float s_k[NTOK][HD + 1];
    __shared__ float s_v[NTOK][HD + 1];
    __shared__ __align__(16) unsigned short s_ws[3][DIM][HD]; // per-head q/k/v weight slices (bf16)
    __shared__ float s_p[32][NTOK + 1];                       // score tile (32 query rows)
    __shared__ __align__(16) unsigned short s_o[NTOK][DIM];   // attention output (pre-proj)
    __shared__ float s_red[4][2];

    const bool f32 = (*(const unsigned*)g1 == 0x3F800000u);   // fp32 "1.0" vs bf16 pair 0x3F803F80

    const int tid = threadIdx.x;
    const int b   = blockIdx.x >> 8;
    const int wid = blockIdx.x & 255;
    const int wp  = wid >> 4;            // window row  (0..15)
    const int wq  = wid & 15;            // window col  (0..15)

    // ---------- LN1 + shifted-window gather ----------
    {
        const int c  = tid & 127;
        const int tg = tid >> 7;
        const float gsc = ld(g1, c, f32);
        const float bsc = ld(b1, c, f32);
        for (int t0 = 0; t0 < NTOK; t0 += 2) {
            const int t  = t0 + tg;
            const int th = t >> 5, tw = t & 31;
            const int gh = (wp * WIN_H + th + SHIFT_H) & (IMG_H - 1);
            const int gw = (wq * WIN_W + tw + SHIFT_W) & (IMG_W - 1);
            const size_t gi = (((size_t)b * IMG_H + gh) * IMG_W + gw) * DIM + c;
            const float v = ld(x, gi, f32);
            float s = v, s2 = v * v;
            #pragma unroll
            for (int off = 32; off; off >>= 1) {
                s  += __shfl_down(s, off);
                s2 += __shfl_down(s2, off);
            }
            if ((tid & 63) == 0) { s_red[tid >> 6][0] = s; s_red[tid >> 6][1] = s2; }
            __syncthreads();
            const float sum = s_red[tg * 2][0] + s_red[tg * 2 + 1][0];
            const float sq  = s_red[tg * 2][1] + s_red[tg * 2 + 1][1];
            const float mean = sum * (1.0f / DIM);
            const float var  = sq * (1.0f / DIM) - mean * mean;
            const float rs   = rsqrtf(var + 1e-5f);
            s_xw[t][c] = f2bf((v - mean) * rs * gsc + bsc);
            __syncthreads();
        }
    }

    // ---------- per-head attention ----------
    for (int hh = 0; hh < HEADS; ++hh) {
        for (int i = tid; i < 3 * DIM * HD; i += 256) {
            const int part = i >> 12;        // 0=q 1=k 2=v
            const int rem  = i & 4095;
            const int kc   = rem >> 5;
            const int d    = rem & 31;
            s_ws[part][kc][d] = f2bf(ld(qkv_w, (size_t)kc * (3 * DIM) + part * DIM + hh * HD + d, f32));
        }
        __syncthreads();
        // qkv projection for this head (fp32 accum)
        {
            const int d2 = (tid & 15) * 2;
            const int tg = tid >> 4;                   // 0..15
            const float bq0 = ld(qkv_b, hh * HD + d2, f32);
            const float bq1 = ld(qkv_b, hh * HD + d2 + 1, f32);
            const float bk0 = ld(qkv_b, DIM + hh * HD + d2, f32);
            const float bk1 = ld(qkv_b, DIM + hh * HD + d2 + 1, f32);
            const float bv0 = ld(qkv_b, 2 * DIM + hh * HD + d2, f32);
            const float bv1 = ld(qkv_b, 2 * DIM + hh * HD + d2 + 1, f32);
            for (int tb = 0; tb < NTOK; tb += 16) {
                const int t = tb + tg;
                float aq0 = 0, aq1 = 0, ak0 = 0, ak1 = 0, av0 = 0, av1 = 0;
                for (int kc = 0; kc < DIM; ++kc) {
                    const float xv = bf2f(s_xw[t][kc]);
                    const unsigned wqv = *(const unsigned*)&s_ws[0][kc][d2];
                    const unsigned wkv = *(const unsigned*)&s_ws[1][kc][d2];
                    const unsigned wvv = *(const unsigned*)&s_ws[2][kc][d2];
                    aq0 += xv * bflo(wqv); aq1 += xv * bfhi(wqv);
                    ak0 += xv * bflo(wkv); ak1 += xv * bfhi(wkv);
                    av0 += xv * bflo(wvv); av1 += xv * bfhi(wvv);
                }
                s_q[t][d2]     = (aq0 + bq0) * QK_SCALE;
                s_q[t][d2 + 1] = (aq1 + bq1) * QK_SCALE;
                s_k[t][d2]     = ak0 + bk0;
                s_k[t][d2 + 1] = ak1 + bk1;
                s_v[t][d2]     = av0 + bv0;
                s_v[t][d2 + 1] = av1 + bv1;
            }
        }
        __syncthreads();
        // attention over 32-query-row tiles
        {
            const int r  = tid >> 3;    // 0..31 query row in tile
            const int cg = tid & 7;     // 0..7 column group
            for (int qb = 0; qb < NTOK; qb += 32) {
                const int qt = qb + r;
                const int qh_ = qt >> 5, qw_ = qt & 31;
                const int gh0 = wp * WIN_H + qh_;
                const int gw0 = wq * WIN_W + qw_;
                const int rgq = ((gh0 < IMG_H - WIN_H) ? 0 : (gh0 < IMG_H - SHIFT_H ? 1 : 2)) * 3
                              + ((gw0 < IMG_W - WIN_W) ? 0 : (gw0 < IMG_W - SHIFT_W ? 1 : 2));
                float qreg[HD];
                #pragma unroll
                for (int d = 0; d < HD; ++d) qreg[d] = s_q[qt][d];
                float pv[16];
                float mx = -1e30f;
                for (int jj = 0; jj < 16; ++jj) {
                    const int j = cg + jj * 8;
                    float acc = 0.f;
                    #pragma unroll
                    for (int d = 0; d < HD; ++d) acc += qreg[d] * s_k[j][d];
                    const int jh = j >> 5, jw = j & 31;
                    acc += ld(rpb, (size_t)((qh_ - jh + WIN_H - 1) * (2 * WIN_W - 1)
                                     + (qw_ - jw + WIN_W - 1)) * HEADS + hh, f32);
                    const int gh1 = wp * WIN_H + jh;
                    const int gw1 = wq * WIN_W + jw;
                    const int rgj = ((gh1 < IMG_H - WIN_H) ? 0 : (gh1 < IMG_H - SHIFT_H ? 1 : 2)) * 3
                                  + ((gw1 < IMG_W - WIN_W) ? 0 : (gw1 < IMG_W - SHIFT_W ? 1 : 2));
                    if (rgj != rgq) acc -= 100.f;
                    pv[jj] = acc;
                    mx = fmaxf(mx, acc);
                }
                #pragma unroll
                for (int off = 1; off < 8; off <<= 1) mx = fmaxf(mx, __shfl_xor(mx, off));
                float den = 0.f;
                #pragma unroll
                for (int jj = 0; jj < 16; ++jj) { pv[jj] = expf(pv[jj] - mx); den += pv[jj]; }
                #pragma unroll
                for (int off = 1; off < 8; off <<= 1) den += __shfl_xor(den, off);
                const float inv = 1.0f / den;
                #pragma unroll
                for (int jj = 0; jj < 16; ++jj) s_p[r][cg + jj * 8] = pv[jj] * inv;
                __syncthreads();
                float oa0 = 0, oa1 = 0, oa2 = 0, oa3 = 0;
                for (int j = 0; j < NTOK; ++j) {
                    const float p = s_p[r][j];
                    oa0 += p * s_v[j][cg];
                    oa1 += p * s_v[j][cg + 8];
                    oa2 += p * s_v[j][cg + 16];
                    oa3 += p * s_v[j][cg + 24];
                }
                s_o[qt][hh * HD + cg]      = f2bf(oa0);
                s_o[qt][hh * HD + cg + 8]  = f2bf(oa1);
                s_o[qt][hh * HD + cg + 16] = f2bf(oa2);
                s_o[qt][hh * HD + cg + 24] = f2bf(oa3);
                __syncthreads();
            }
        }
    }

    // ---------- stage proj_w into s_xw (xw no longer needed), converting to bf16 ----------
    {
        unsigned short* dst = &s_xw[0][0];
        for (int i = tid; i < DIM * DIM; i += 256) dst[i] = f2bf(ld(proj_w, i, f32));
    }
    __syncthreads();

    // ---------- proj + residual + un-shift scatter ----------
    {
        const int c0 = (tid & 31) * 4;
        const int tg = tid >> 5;   // 0..7
        const float pb0 = ld(proj_b, c0, f32),     pb1 = ld(proj_b, c0 + 1, f32);
        const float pb2 = ld(proj_b, c0 + 2, f32), pb3 = ld(proj_b, c0 + 3, f32);
        for (int t0 = 0; t0 < NTOK; t0 += 8) {
            const int t = t0 + tg;
            float a0 = pb0, a1 = pb1, a2 = pb2, a3 = pb3;
            for (int j = 0; j < DIM; ++j) {
                const float ov = bf2f(s_o[t][j]);
                const uint2 wb = *(const uint2*)&s_xw[j][c0];   // == proj_w[j*128 + c0..c0+3]
                a0 += ov * bflo(wb.x); a1 += ov * bfhi(wb.x);
                a2 += ov * bflo(wb.y); a3 += ov * bfhi(wb.y);
            }
            const int th = t >> 5, tw = t & 31;
            const int gh = (wp * WIN_H + th + SHIFT_H) & (IMG_H - 1);
            const int gw = (wq * WIN_W + tw + SHIFT_W) & (IMG_W - 1);
            const size_t gi = (((size_t)b * IMG_H + gh) * IMG_W + gw) * DIM + c0;
            st(out, gi + 0, f32, ld(x, gi + 0, f32) + a0);
            st(out, gi + 1, f32, ld(x, gi + 1, f32) + a1);
            st(out, gi + 2, f32, ld(x, gi + 2, f32) + a2);
            st(out, gi + 3, f32, ld(x, gi + 3, f32) + a3);
        }
    }
}

// ---------------------------------------------------------------------------
// Kernel 2: LN2 + MLP (fc1 -> exact GELU -> fc2) + residual, in-place on out
// One block (256 threads) per 16 tokens; weights staged (bf16) in LDS.
// ---------------------------------------------------------------------------
__global__ __launch_bounds__(256) void swin_mlp_kernel(
    const void* __restrict__ g2,
    const void* __restrict__ beta2,
    const void* __restrict__ fc1_w,
    const void* __restrict__ fc1_b,
    const void* __restrict__ fc2_w,
    const void* __restrict__ fc2_b,
    void* __restrict__ out)
{
    __shared__ __align__(16) unsigned short s_w[DIM * 4 * DIM];   // 128 KB weight stage (bf16)
    __shared__ __align__(16) unsigned short s_x[16][DIM];         // LN'd tokens (bf16)
    __shared__ float s_res[16][DIM];                              // residual (exact)
    __shared__ __align__(16) unsigned short s_h[16][4 * DIM];     // hidden activations (bf16)
    __shared__ float s_red[4][2];

    const bool f32 = (*(const unsigned*)g2 == 0x3F800000u);

    const int tid = threadIdx.x;
    const size_t tok0 = (size_t)blockIdx.x * 16;

    // stage fc1_w (128x512) -> bf16
    for (int i = tid; i < DIM * 4 * DIM; i += 256) s_w[i] = f2bf(ld(fc1_w, i, f32));
    // LN2 on 16 tokens (x_mid read from out)
    {
        const int c  = tid & 127;
        const int tg = tid >> 7;
        const float gsc = ld(g2, c, f32);
        const float bsc = ld(beta2, c, f32);
        for (int t0 = 0; t0 < 16; t0 += 2) {
            const int tt = t0 + tg;
            const size_t gi = (tok0 + tt) * DIM + c;
            const float v = ld(out, gi, f32);
            float s = v, s2 = v * v;
            #pragma unroll
            for (int off = 32; off; off >>= 1) { s += __shfl_down(s, off); s2 += __shfl_down(s2, off); }
            if ((tid & 63) == 0) { s_red[tid >> 6][0] = s; s_red[tid >> 6][1] = s2; }
            __syncthreads();
            const float sum = s_red[tg * 2][0] + s_red[tg * 2 + 1][0];
            const float sq  = s_red[tg * 2][1] + s_red[tg * 2 + 1][1];
            const float mean = sum * (1.0f / DIM);
            const float var  = sq * (1.0f / DIM) - mean * mean;
            const float rs   = rsqrtf(var + 1e-5f);
            s_res[tt][c] = v;
            s_x[tt][c]   = f2bf((v - mean) * rs * gsc + bsc);
            __syncthreads();
        }
    }
    // fc1 + exact GELU
    {
        const int c0 = (tid & 127) * 4;
        const int tg = tid >> 7;
        const float w0 = ld(fc1_b, c0, f32),     w1 = ld(fc1_b, c0 + 1, f32);
        const float w2 = ld(fc1_b, c0 + 2, f32), w3 = ld(fc1_b, c0 + 3, f32);
        for (int p = 0; p < 8; ++p) {
            const int tt = p * 2 + tg;
            float a0 = w0, a1 = w1, a2 = w2, a3 = w3;
            for (int k = 0; k < DIM; ++k) {
                const float xv = bf2f(s_x[tt][k]);
                const uint2 wb = *(const uint2*)&s_w[k * (4 * DIM) + c0];
                a0 += xv * bflo(wb.x); a1 += xv * bfhi(wb.x);
                a2 += xv * bflo(wb.y); a3 += xv * bfhi(wb.y);
            }
            a0 = 0.5f * a0 * (1.f + erff(a0 * 0.70710678118654752f));
            a1 = 0.5f * a1 * (1.f + erff(a1 * 0.70710678118654752f));
            a2 = 0.5f * a2 * (1.f + erff(a2 * 0.70710678118654752f));
            a3 = 0.5f * a3 * (1.f + erff(a3 * 0.70710678118654752f));
            s_h[tt][c0]     = f2bf(a0);
            s_h[tt][c0 + 1] = f2bf(a1);
            s_h[tt][c0 + 2] = f2bf(a2);
            s_h[tt][c0 + 3] = f2bf(a3);
        }
    }
    __syncthreads();
    // stage fc2_w (512x128) -> bf16
    for (int i = tid; i < 4 * DIM * DIM; i += 256) s_w[i] = f2bf(ld(fc2_w, i, f32));
    __syncthreads();
    // fc2 + residual
    {
        const int c0 = (tid & 31) * 4;
        const int tg = tid >> 5;   // 0..7
        const float w0 = ld(fc2_b, c0, f32),     w1 = ld(fc2_b, c0 + 1, f32);
        const float w2 = ld(fc2_b, c0 + 2, f32), w3 = ld(fc2_b, c0 + 3, f32);
        for (int p = 0; p < 2; ++p) {
            const int tt = p * 8 + tg;
            float a0 = w0, a1 = w1, a2 = w2, a3 = w3;
            for (int k = 0; k < 4 * DIM; ++k) {
                const float hv = bf2f(s_h[tt][k]);
                const uint2 wb = *(const uint2*)&s_w[k * DIM + c0];
                a0 += hv * bflo(wb.x); a1 += hv * bfhi(wb.x);
                a2 += hv * bflo(wb.y); a3 += hv * bfhi(wb.y);
            }
            const size_t gi = (tok0 + tt) * DIM + c0;
            st(out, gi + 0, f32, s_res[tt][c0 + 0] + a0);
            st(out, gi + 1, f32, s_res[tt][c0 + 1] + a1);
            st(out, gi + 2, f32, s_res[tt][c0 + 2] + a2);
            st(out, gi + 3, f32, s_res[tt][c0 + 3] + a3);
        }
    }
}

extern "C" void kernel_launch(void* const* d_in, const int* in_sizes, int n_in,
                              void* d_out, int out_size, void* d_ws, size_t ws_size,
                              hipStream_t stream) {
    (void)in_sizes; (void)n_in; (void)d_ws; (void)ws_size; (void)out_size;
    const void* x      = d_in[0];
    const void* g1     = d_in[1];
    const void* b1     = d_in[2];
    const void* qkv_w  = d_in[3];
    const void* qkv_b  = d_in[4];
    const void* rpb    = d_in[5];
    const void* proj_w = d_in[6];
    const void* proj_b = d_in[7];
    const void* g2     = d_in[8];
    const void* bb2    = d_in[9];
    const void* fc1_w  = d_in[10];
    const void* fc1_b  = d_in[11];
    const void* fc2_w  = d_in[12];
    const void* fc2_b  = d_in[13];

    hipLaunchKernelGGL(swin_attn_kernel, dim3(BATCH * 256), dim3(256), 0, stream,
                       x, g1, b1, qkv_w, qkv_b, rpb, proj_w, proj_b, d_out);
    hipLaunchKernelGGL(swin_mlp_kernel, dim3(BATCH * IMG_H * IMG_W / 16), dim3(256), 0, stream,
                       g2, bb2, fc1_w, fc1_b, fc2_w, fc2_b, d_out);
}

// Round 3
// 3962.110 us; speedup vs baseline: 2.9910x; 2.9910x over previous
//
#include <hip/hip_runtime.h>
#include <hip/hip_bf16.h>
#include <math.h>

constexpr int BATCH = 8;
constexpr int IMG_H = 64;
constexpr int IMG_W = 512;
constexpr int DIM   = 128;
constexpr int WIN_H = 4, WIN_W = 32;
constexpr int SHIFT_H = 2, SHIFT_W = 2;
constexpr int NTOK = 128;            // tokens per window
constexpr int HEADS = 4, HD = 32;
constexpr float QK_SCALE = 0.17677669529663687f;   // 1/sqrt(32)

typedef __attribute__((ext_vector_type(8))) short bf16x8;
typedef __attribute__((ext_vector_type(4))) float f32x4;

__device__ __forceinline__ float bf2f(unsigned short u) {
    return __uint_as_float(((unsigned)u) << 16);
}
__device__ __forceinline__ float bflo(unsigned u) { return __uint_as_float(u << 16); }
__device__ __forceinline__ float bfhi(unsigned u) { return __uint_as_float(u & 0xffff0000u); }
__device__ __forceinline__ unsigned short f2bf(float f) {
    unsigned u = __float_as_uint(f);
    u = (u + 0x7fffu + ((u >> 16) & 1u)) >> 16;   // RNE
    return (unsigned short)u;
}
// dtype confirmed fp32 (R2: WRITE_SIZE == 33.5M * 4B); helpers kept for attn kernel
__device__ __forceinline__ float ld(const void* p, size_t i, bool f32) {
    return f32 ? ((const float*)p)[i] : bf2f(((const unsigned short*)p)[i]);
}
__device__ __forceinline__ void st(void* p, size_t i, bool f32, float v) {
    if (f32) ((float*)p)[i] = v;
    else     ((unsigned short*)p)[i] = f2bf(v);
}

// ---------------------------------------------------------------------------
// Kernel 0: convert MLP weights to bf16, transposed (B^T layout for b-frags)
// w1t[n][k] = fc1_w[k][n]  (n<512, k<128)
// w2t[n][k] = fc2_w[k][n]  (n<128, k<512)
// ---------------------------------------------------------------------------
__global__ __launch_bounds__(256) void prep_weights(
    const float* __restrict__ fc1_w, const float* __restrict__ fc2_w,
    unsigned short* __restrict__ w1t, unsigned short* __restrict__ w2t)
{
    const int tid = blockIdx.x * 256 + threadIdx.x;
    if (tid < 512 * 128) {
        const int n = tid >> 7, k = tid & 127;
        w1t[tid] = f2bf(fc1_w[k * 512 + n]);
    } else if (tid < 2 * 512 * 128) {
        const int t = tid - 512 * 128;
        const int n = t >> 9, k = t & 511;
        w2t[t] = f2bf(fc2_w[k * 128 + n]);
    }
}

// ---------------------------------------------------------------------------
// Kernel 1: LN1 + cyclic shift + window attention + proj + residual (as R2)
// ---------------------------------------------------------------------------
__global__ __launch_bounds__(256) void swin_attn_kernel(
    const void* __restrict__ x,
    const void* __restrict__ g1,
    const void* __restrict__ b1,
    const void* __restrict__ qkv_w,
    const void* __restrict__ qkv_b,
    const void* __restrict__ rpb,
    const void* __restrict__ proj_w,
    const void* __restrict__ proj_b,
    void* __restrict__ out)
{
    __shared__ __align__(16) unsigned short s_xw[NTOK][DIM];
    __shared__ float s_q[NTOK][HD + 1];
    __shared__ float s_k[NTOK][HD + 1];
    __shared__ float s_v[NTOK][HD + 1];
    __shared__ __align__(16) unsigned short s_ws[3][DIM][HD];
    __shared__ float s_p[32][NTOK + 1];
    __shared__ __align__(16) unsigned short s_o[NTOK][DIM];
    __shared__ float s_red[4][2];

    const bool f32 = true;   // confirmed fp32 via R2 WRITE_SIZE

    const int tid = threadIdx.x;
    const int b   = blockIdx.x >> 8;
    const int wid = blockIdx.x & 255;
    const int wp  = wid >> 4;
    const int wq  = wid & 15;

    {
        const int c  = tid & 127;
        const int tg = tid >> 7;
        const float gsc = ld(g1, c, f32);
        const float bsc = ld(b1, c, f32);
        for (int t0 = 0; t0 < NTOK; t0 += 2) {
            const int t  = t0 + tg;
            const int th = t >> 5, tw = t & 31;
            const int gh = (wp * WIN_H + th + SHIFT_H) & (IMG_H - 1);
            const int gw = (wq * WIN_W + tw + SHIFT_W) & (IMG_W - 1);
            const size_t gi = (((size_t)b * IMG_H + gh) * IMG_W + gw) * DIM + c;
            const float v = ld(x, gi, f32);
            float s = v, s2 = v * v;
            #pragma unroll
            for (int off = 32; off; off >>= 1) {
                s  += __shfl_down(s, off);
                s2 += __shfl_down(s2, off);
            }
            if ((tid & 63) == 0) { s_red[tid >> 6][0] = s; s_red[tid >> 6][1] = s2; }
            __syncthreads();
            const float sum = s_red[tg * 2][0] + s_red[tg * 2 + 1][0];
            const float sq  = s_red[tg * 2][1] + s_red[tg * 2 + 1][1];
            const float mean = sum * (1.0f / DIM);
            const float var  = sq * (1.0f / DIM) - mean * mean;
            const float rs   = rsqrtf(var + 1e-5f);
            s_xw[t][c] = f2bf((v - mean) * rs * gsc + bsc);
            __syncthreads();
        }
    }

    for (int hh = 0; hh < HEADS; ++hh) {
        for (int i = tid; i < 3 * DIM * HD; i += 256) {
            const int part = i >> 12;
            const int rem  = i & 4095;
            const int kc   = rem >> 5;
            const int d    = rem & 31;
            s_ws[part][kc][d] = f2bf(ld(qkv_w, (size_t)kc * (3 * DIM) + part * DIM + hh * HD + d, f32));
        }
        __syncthreads();
        {
            const int d2 = (tid & 15) * 2;
            const int tg = tid >> 4;
            const float bq0 = ld(qkv_b, hh * HD + d2, f32);
            const float bq1 = ld(qkv_b, hh * HD + d2 + 1, f32);
            const float bk0 = ld(qkv_b, DIM + hh * HD + d2, f32);
            const float bk1 = ld(qkv_b, DIM + hh * HD + d2 + 1, f32);
            const float bv0 = ld(qkv_b, 2 * DIM + hh * HD + d2, f32);
            const float bv1 = ld(qkv_b, 2 * DIM + hh * HD + d2 + 1, f32);
            for (int tb = 0; tb < NTOK; tb += 16) {
                const int t = tb + tg;
                float aq0 = 0, aq1 = 0, ak0 = 0, ak1 = 0, av0 = 0, av1 = 0;
                for (int kc = 0; kc < DIM; ++kc) {
                    const float xv = bf2f(s_xw[t][kc]);
                    const unsigned wqv = *(const unsigned*)&s_ws[0][kc][d2];
                    const unsigned wkv = *(const unsigned*)&s_ws[1][kc][d2];
                    const unsigned wvv = *(const unsigned*)&s_ws[2][kc][d2];
                    aq0 += xv * bflo(wqv); aq1 += xv * bfhi(wqv);
                    ak0 += xv * bflo(wkv); ak1 += xv * bfhi(wkv);
                    av0 += xv * bflo(wvv); av1 += xv * bfhi(wvv);
                }
                s_q[t][d2]     = (aq0 + bq0) * QK_SCALE;
                s_q[t][d2 + 1] = (aq1 + bq1) * QK_SCALE;
                s_k[t][d2]     = ak0 + bk0;
                s_k[t][d2 + 1] = ak1 + bk1;
                s_v[t][d2]     = av0 + bv0;
                s_v[t][d2 + 1] = av1 + bv1;
            }
        }
        __syncthreads();
        {
            const int r  = tid >> 3;
            const int cg = tid & 7;
            for (int qb = 0; qb < NTOK; qb += 32) {
                const int qt = qb + r;
                const int qh_ = qt >> 5, qw_ = qt & 31;
                const int gh0 = wp * WIN_H + qh_;
                const int gw0 = wq * WIN_W + qw_;
                const int rgq = ((gh0 < IMG_H - WIN_H) ? 0 : (gh0 < IMG_H - SHIFT_H ? 1 : 2)) * 3
                              + ((gw0 < IMG_W - WIN_W) ? 0 : (gw0 < IMG_W - SHIFT_W ? 1 : 2));
                float qreg[HD];
                #pragma unroll
                for (int d = 0; d < HD; ++d) qreg[d] = s_q[qt][d];
                float pv[16];
                float mx = -1e30f;
                for (int jj = 0; jj < 16; ++jj) {
                    const int j = cg + jj * 8;
                    float acc = 0.f;
                    #pragma unroll
                    for (int d = 0; d < HD; ++d) acc += qreg[d] * s_k[j][d];
                    const int jh = j >> 5, jw = j & 31;
                    acc += ld(rpb, (size_t)((qh_ - jh + WIN_H - 1) * (2 * WIN_W - 1)
                                     + (qw_ - jw + WIN_W - 1)) * HEADS + hh, f32);
                    const int gh1 = wp * WIN_H + jh;
                    const int gw1 = wq * WIN_W + jw;
                    const int rgj = ((gh1 < IMG_H - WIN_H) ? 0 : (gh1 < IMG_H - SHIFT_H ? 1 : 2)) * 3
                                  + ((gw1 < IMG_W - WIN_W) ? 0 : (gw1 < IMG_W - SHIFT_W ? 1 : 2));
                    if (rgj != rgq) acc -= 100.f;
                    pv[jj] = acc;
                    mx = fmaxf(mx, acc);
                }
                #pragma unroll
                for (int off = 1; off < 8; off <<= 1) mx = fmaxf(mx, __shfl_xor(mx, off));
                float den = 0.f;
                #pragma unroll
                for (int jj = 0; jj < 16; ++jj) { pv[jj] = expf(pv[jj] - mx); den += pv[jj]; }
                #pragma unroll
                for (int off = 1; off < 8; off <<= 1) den += __shfl_xor(den, off);
                const float inv = 1.0f / den;
                #pragma unroll
                for (int jj = 0; jj < 16; ++jj) s_p[r][cg + jj * 8] = pv[jj] * inv;
                __syncthreads();
                float oa0 = 0, oa1 = 0, oa2 = 0, oa3 = 0;
                for (int j = 0; j < NTOK; ++j) {
                    const float p = s_p[r][j];
                    oa0 += p * s_v[j][cg];
                    oa1 += p * s_v[j][cg + 8];
                    oa2 += p * s_v[j][cg + 16];
                    oa3 += p * s_v[j][cg + 24];
                }
                s_o[qt][hh * HD + cg]      = f2bf(oa0);
                s_o[qt][hh * HD + cg + 8]  = f2bf(oa1);
                s_o[qt][hh * HD + cg + 16] = f2bf(oa2);
                s_o[qt][hh * HD + cg + 24] = f2bf(oa3);
                __syncthreads();
            }
        }
    }

    {
        unsigned short* dst = &s_xw[0][0];
        for (int i = tid; i < DIM * DIM; i += 256) dst[i] = f2bf(ld(proj_w, i, f32));
    }
    __syncthreads();

    {
        const int c0 = (tid & 31) * 4;
        const int tg = tid >> 5;
        const float pb0 = ld(proj_b, c0, f32),     pb1 = ld(proj_b, c0 + 1, f32);
        const float pb2 = ld(proj_b, c0 + 2, f32), pb3 = ld(proj_b, c0 + 3, f32);
        for (int t0 = 0; t0 < NTOK; t0 += 8) {
            const int t = t0 + tg;
            float a0 = pb0, a1 = pb1, a2 = pb2, a3 = pb3;
            for (int j = 0; j < DIM; ++j) {
                const float ov = bf2f(s_o[t][j]);
                const uint2 wb = *(const uint2*)&s_xw[j][c0];
                a0 += ov * bflo(wb.x); a1 += ov * bfhi(wb.x);
                a2 += ov * bflo(wb.y); a3 += ov * bfhi(wb.y);
            }
            const int th = t >> 5, tw = t & 31;
            const int gh = (wp * WIN_H + th + SHIFT_H) & (IMG_H - 1);
            const int gw = (wq * WIN_W + tw + SHIFT_W) & (IMG_W - 1);
            const size_t gi = (((size_t)b * IMG_H + gh) * IMG_W + gw) * DIM + c0;
            st(out, gi + 0, f32, ld(x, gi + 0, f32) + a0);
            st(out, gi + 1, f32, ld(x, gi + 1, f32) + a1);
            st(out, gi + 2, f32, ld(x, gi + 2, f32) + a2);
            st(out, gi + 3, f32, ld(x, gi + 3, f32) + a3);
        }
    }
}

// ---------------------------------------------------------------------------
// Kernel 2 (NEW): LN2 + MLP via MFMA. 64 tokens/block, 256 threads (4 waves),
// hidden processed in 8 chunks of 64. LDS ~62.5 KB -> 2 blocks/CU.
// ---------------------------------------------------------------------------
__global__ __launch_bounds__(256) void swin_mlp_mfma(
    const float* __restrict__ g2, const float* __restrict__ beta2,
    const unsigned short* __restrict__ w1t,   // [512][128] bf16 (fc1_w^T)
    const float* __restrict__ fc1_b,
    const unsigned short* __restrict__ w2t,   // [128][512] bf16 (fc2_w^T)
    const float* __restrict__ fc2_b,
    float* __restrict__ out)
{
    __shared__ __align__(16) unsigned short s_x[64][136];    // LN'd tokens [m][k]
    __shared__ __align__(16) unsigned short s_h[64][72];     // hidden chunk [m][k]
    __shared__ __align__(16) unsigned short s_w1[64][136];   // w1 chunk B^T [n][k]
    __shared__ __align__(16) unsigned short s_w2[128][72];   // w2 chunk B^T [n][k]

    const int tid = threadIdx.x;
    const int wv  = tid >> 6;
    const int ln  = tid & 63;
    const int m0  = wv * 16;                 // wave-owned token rows
    const size_t tok0 = (size_t)blockIdx.x * 64;

    // ---- LN2: each half-wave handles one token (32 lanes x float4) ----
    {
        const int lh = ln & 31;
        const int hf = ln >> 5;
        const float4 gv = *(const float4*)&g2[lh * 4];
        const float4 bv = *(const float4*)&beta2[lh * 4];
        for (int it = 0; it < 8; ++it) {
            const int t = m0 + it * 2 + hf;
            const float4 v = *(const float4*)&out[(tok0 + t) * 128 + lh * 4];
            float s  = v.x + v.y + v.z + v.w;
            float s2 = v.x * v.x + v.y * v.y + v.z * v.z + v.w * v.w;
            #pragma unroll
            for (int off = 1; off < 32; off <<= 1) {
                s  += __shfl_xor(s, off);
                s2 += __shfl_xor(s2, off);
            }
            const float mean = s * (1.0f / 128.0f);
            const float var  = s2 * (1.0f / 128.0f) - mean * mean;
            const float rs   = rsqrtf(var + 1e-5f);
            const unsigned short o0 = f2bf((v.x - mean) * rs * gv.x + bv.x);
            const unsigned short o1 = f2bf((v.y - mean) * rs * gv.y + bv.y);
            const unsigned short o2 = f2bf((v.z - mean) * rs * gv.z + bv.z);
            const unsigned short o3 = f2bf((v.w - mean) * rs * gv.w + bv.w);
            uint2 pk;
            pk.x = (unsigned)o0 | ((unsigned)o1 << 16);
            pk.y = (unsigned)o2 | ((unsigned)o3 << 16);
            *(uint2*)&s_x[t][lh * 4] = pk;
        }
    }

    f32x4 acc_o[8];
    #pragma unroll
    for (int i = 0; i < 8; ++i) acc_o[i] = (f32x4){0.f, 0.f, 0.f, 0.f};

    const int ar = m0 + (ln & 15);          // a-frag row
    const int nr = ln & 15;                 // b-frag n within tile
    const int kq = (ln >> 4) * 8;           // k quad offset
    const int dr = m0 + (ln >> 4) * 4;      // D-frag row base

    for (int c = 0; c < 8; ++c) {
        // stage w1 chunk (rows c*64..+63, k 0..127) and w2 chunk (rows 0..127, k c*64..+63)
        for (int j = tid; j < 1024; j += 256) {
            const int row = j >> 4, c8 = j & 15;
            *(uint4*)&s_w1[row][c8 * 8] = *(const uint4*)&w1t[(size_t)(c * 64 + row) * 128 + c8 * 8];
        }
        for (int j = tid; j < 1024; j += 256) {
            const int row = j >> 3, c8 = j & 7;
            *(uint4*)&s_w2[row][c8 * 8] = *(const uint4*)&w2t[(size_t)row * 512 + c * 64 + c8 * 8];
        }
        __syncthreads();
        // GEMM1: h(16x64 per wave) = x_ln(16x128) @ w1c(128x64)
        f32x4 hA[4];
        #pragma unroll
        for (int i = 0; i < 4; ++i) hA[i] = (f32x4){0.f, 0.f, 0.f, 0.f};
        #pragma unroll
        for (int ks = 0; ks < 4; ++ks) {
            const bf16x8 a = *(const bf16x8*)&s_x[ar][ks * 32 + kq];
            #pragma unroll
            for (int nt = 0; nt < 4; ++nt) {
                const bf16x8 bb = *(const bf16x8*)&s_w1[nt * 16 + nr][ks * 32 + kq];
                hA[nt] = __builtin_amdgcn_mfma_f32_16x16x32_bf16(a, bb, hA[nt], 0, 0, 0);
            }
        }
        // bias + exact GELU, write hidden chunk (wave-private rows)
        #pragma unroll
        for (int nt = 0; nt < 4; ++nt) {
            const float bias = fc1_b[c * 64 + nt * 16 + nr];
            #pragma unroll
            for (int r = 0; r < 4; ++r) {
                float v = hA[nt][r] + bias;
                v = 0.5f * v * (1.0f + erff(v * 0.70710678118654752f));
                s_h[dr + r][nt * 16 + nr] = f2bf(v);
            }
        }
        __syncthreads();
        // GEMM2: acc_o += h(16x64) @ w2c(64x128)
        #pragma unroll
        for (int ks = 0; ks < 2; ++ks) {
            const bf16x8 a = *(const bf16x8*)&s_h[ar][ks * 32 + kq];
            #pragma unroll
            for (int nt = 0; nt < 8; ++nt) {
                const bf16x8 bb = *(const bf16x8*)&s_w2[nt * 16 + nr][ks * 32 + kq];
                acc_o[nt] = __builtin_amdgcn_mfma_f32_16x16x32_bf16(a, bb, acc_o[nt], 0, 0, 0);
            }
        }
        __syncthreads();
    }

    // ---- epilogue: out += mlp(out_ln) + fc2_b  (residual re-read, L2-hot) ----
    #pragma unroll
    for (int nt = 0; nt < 8; ++nt) {
        const float bias = fc2_b[nt * 16 + nr];
        #pragma unroll
        for (int r = 0; r < 4; ++r) {
            const size_t gi = (tok0 + dr + r) * 128 + nt * 16 + nr;
            out[gi] = out[gi] + acc_o[nt][r] + bias;
        }
    }
}

extern "C" void kernel_launch(void* const* d_in, const int* in_sizes, int n_in,
                              void* d_out, int out_size, void* d_ws, size_t ws_size,
                              hipStream_t stream) {
    (void)in_sizes; (void)n_in; (void)out_size; (void)ws_size;
    const void* x      = d_in[0];
    const void* g1     = d_in[1];
    const void* b1     = d_in[2];
    const void* qkv_w  = d_in[3];
    const void* qkv_b  = d_in[4];
    const void* rpb    = d_in[5];
    const void* proj_w = d_in[6];
    const void* proj_b = d_in[7];
    const float* g2    = (const float*)d_in[8];
    const float* bb2   = (const float*)d_in[9];
    const float* fc1_w = (const float*)d_in[10];
    const float* fc1_b = (const float*)d_in[11];
    const float* fc2_w = (const float*)d_in[12];
    const float* fc2_b = (const float*)d_in[13];

    unsigned short* w1t = (unsigned short*)d_ws;                 // 512*128 bf16
    unsigned short* w2t = w1t + 512 * 128;                       // 128*512 bf16

    hipLaunchKernelGGL(prep_weights, dim3(512), dim3(256), 0, stream,
                       fc1_w, fc2_w, w1t, w2t);
    hipLaunchKernelGGL(swin_attn_kernel, dim3(BATCH * 256), dim3(256), 0, stream,
                       x, g1, b1, qkv_w, qkv_b, rpb, proj_w, proj_b, d_out);
    hipLaunchKernelGGL(swin_mlp_mfma, dim3(BATCH * IMG_H * IMG_W / 64), dim3(256), 0, stream,
                       g2, bb2, w1t, fc1_b, w2t, fc2_b, (float*)d_out);
}